// Round 1
// 5348.744 us; speedup vs baseline: 1.1930x; 1.1930x over previous
//
#include <hip/hip_runtime.h>
#include <stdint.h>

// 2-layer LSTM (B=512,T=1024,I=80,H=160) on MI355X gfx950.
// 2-stage pipeline, 32 groups x 2 = 64 blocks x 512 thr (8 waves, 2 waves/SIMD).
// Round-4 change: SPLIT-ACCUMULATOR PRECOMPUTE. The input-side projection
// (A: Wih0*x(t+1); B: Wih1*h0(t+1)) is accumulated into accx[] in the
// post-barrier shadow of step t, where it also hides the post-barrier
// h-frag ds_read latency. Step t's critical block is then only the 5-deep
// recurrent MFMA chain on pure register operands:
//   A: Whh0 (25 frags, regs);  B: Whh1 (25 frags, regs -- SWAPPED with Wih1
//   kt3,4 which now live in LDS, net-zero regs, no on-path LDS reads).
// accx accumulates in place (init+input part at end of step t-1, recurrent
// part at step t) -> zero extra accumulator registers.
// Ring protocol unchanged: self-validating tags, DEPTH=32, credit every 8.

#define TT 1024
#define BATCH 512
#define II 80
#define HH 160

constexpr int BB    = 16;
constexpr int NGRP  = BATCH / BB;   // 32
constexpr int NW    = 8;
constexpr int NTHR  = NW * 64;      // 512
constexpr int NTILE = 5;            // 40 col-tiles / 8 waves
constexpr int DEPTH = 32;           // ring depth (power of 2)
constexpr int HP    = 168;          // LDS h row stride (shorts)

typedef __attribute__((ext_vector_type(8))) short s8b;
typedef __attribute__((ext_vector_type(4))) float f4;

// ring: per slot, 5 waves x 64 lanes x 3 u64 = 960 u64 = 7680 B
constexpr int SLOT_U64 = 960;
constexpr size_t OFF_RING = 4096;
constexpr size_t RING_STRIDE = (size_t)DEPTH * SLOT_U64 * 8;   // 245760 B/group

// dynamic LDS layout (bytes)
constexpr int HSH_OFF = 81920;    // h dbuf [2][16*HP] shorts (10752)
constexpr int H0L_OFF = 92672;    // B: h0 dbuf [2][16*HP] shorts (10752)
constexpr int YP_OFF  = 103424;   // B: ypart [2][8][16] float (1024)
constexpr int BS_OFF  = 104448;   // B: bias1 [640] float (2560)
constexpr int WO_OFF  = 107008;   // B: wout [160] float (640)
constexpr int SMEM_SZ = 107648;

__device__ __forceinline__ short f2bf(float x){
  uint32_t u = __builtin_bit_cast(uint32_t, x);
  u = (u + 0x7FFFu + ((u >> 16) & 1u)) >> 16;     // RNE (matches __float2bfloat16_rn)
  return (short)u;
}
__device__ __forceinline__ float sigf(float x){ return 1.f/(1.f+__expf(-x)); }
__device__ __forceinline__ float tanh_(float x){ return 1.f - 2.f/(__expf(2.f*x)+1.f); }

__device__ __forceinline__ f4 mfma16(s8b a, s8b b, f4 c){
  return __builtin_amdgcn_mfma_f32_16x16x32_bf16(a, b, c, 0, 0, 0);
}

template<int CTRL>
__device__ __forceinline__ float qperm(float v){
  return __builtin_bit_cast(float,
    __builtin_amdgcn_mov_dpp(__builtin_bit_cast(int, v), CTRL, 0xf, 0xf, true));
}
// intra-quad 4x4 transpose (proven r3): acc[r]=gate q of row lq*4+r -> gv[g]=gate g of row lq*4+q
__device__ __forceinline__ void qtrans(f4 acc, int q, float gv[4]){
  float a0=acc[0], a1=acc[1], a2=acc[2], a3=acc[3];
  float s0 = q==0?a0 : q==1?a1 : q==2?a2 : a3;
  float s1 = q==0?a3 : q==1?a0 : q==2?a1 : a2;
  float s2 = q==0?a2 : q==1?a3 : q==2?a0 : a1;
  float s3 = q==0?a1 : q==1?a2 : q==2?a3 : a0;
  float r0 = s0;
  float r1 = qperm<0x39>(s1);
  float r2 = qperm<0x4E>(s2);
  float r3 = qperm<0x93>(s3);
  gv[0] = q==0?r0 : q==1?r3 : q==2?r2 : r1;
  gv[1] = q==0?r1 : q==1?r0 : q==2?r3 : r2;
  gv[2] = q==0?r2 : q==1?r1 : q==2?r0 : r3;
  gv[3] = q==0?r3 : q==1?r2 : q==2?r1 : r0;
}

__device__ __forceinline__ s8b pack8(float4 a, float4 b){
  s8b r;
  r[0]=f2bf(a.x); r[1]=f2bf(a.y); r[2]=f2bf(a.z); r[3]=f2bf(a.w);
  r[4]=f2bf(b.x); r[5]=f2bf(b.y); r[6]=f2bf(b.z); r[7]=f2bf(b.w);
  return r;
}
__device__ __forceinline__ float4 ld4(const float* p){ return *(const float4*)p; }
__device__ __forceinline__ s8b wfrag(const float* p){ return pack8(ld4(p), ld4(p+4)); }

__device__ __forceinline__ void st64(unsigned long long* p, unsigned long long v){
  __hip_atomic_store(p, v, __ATOMIC_RELAXED, __HIP_MEMORY_SCOPE_AGENT);
}
__device__ __forceinline__ unsigned long long ld64(const unsigned long long* p){
  return __hip_atomic_load(p, __ATOMIC_RELAXED, __HIP_MEMORY_SCOPE_AGENT);
}
__device__ __forceinline__ void poll_ge(int* p, int& shadow, int target, int lane){
  while (shadow < target){
    int v = 0;
    if (lane == 0) v = __hip_atomic_load(p, __ATOMIC_ACQUIRE, __HIP_MEMORY_SCOPE_AGENT);
    shadow = __shfl(v, 0, 64);
    if (shadow < target) __builtin_amdgcn_s_sleep(2);
  }
}

__global__ __launch_bounds__(NTHR, 1)   // block=512: 2 waves/SIMD -> 256-reg cap
void lstm2(const float* __restrict__ x,
           const float* __restrict__ Wih0, const float* __restrict__ Whh0,
           const float* __restrict__ bih0, const float* __restrict__ bhh0,
           const float* __restrict__ Wih1, const float* __restrict__ Whh1,
           const float* __restrict__ bih1, const float* __restrict__ bhh1,
           const float* __restrict__ Wout, const float* __restrict__ bout,
           float* __restrict__ out, char* __restrict__ ws)
{
  extern __shared__ char smem[];
  const int tid = threadIdx.x;
  const int w   = tid >> 6;
  const int l   = tid & 63;
  const int lq  = l >> 4;
  const int lr  = l & 15;
  const int q   = l & 3;
  const int h2  = (l >> 2) & 3;
  const int stage = blockIdx.x >> 5;
  const int gid   = blockIdx.x & 31;
  const int b0    = gid * BB;

  int* prog = (int*)ws + gid;   // consumer progress (credit to A)
  unsigned long long* ring =
      (unsigned long long*)(ws + OFF_RING + (size_t)gid * RING_STRIDE);

  short* hsh = (short*)(smem + HSH_OFF);                // [2][16*HP]
  const s8b zf = {};

  if (stage == 0){
    // ================= stage A: layer 0 =================
    // Whh0 (25 frags) + Wih0 kt2 (5) in regs; Wih0 kt0,1 (10) in LDS.
    s8b Wh[NTILE][5], Wi2[NTILE];
    float bias0[NTILE];
    #pragma unroll
    for (int s = 0; s < NTILE; ++s){
      const int ct = w + 8*s;
      const int wrow = q*HH + 4*ct + h2;
      bias0[s] = bih0[wrow] + bhh0[wrow];
      #pragma unroll
      for (int kt = 0; kt < 2; ++kt)
        *(s8b*)(smem + ((w*10 + s*2 + kt) << 10) + (l << 4)) =
            wfrag(Wih0 + (size_t)wrow*II + kt*32 + lq*8);
      Wi2[s] = (lq < 2) ? wfrag(Wih0 + (size_t)wrow*II + 64 + lq*8) : zf;
      #pragma unroll
      for (int kt = 0; kt < 5; ++kt)
        Wh[s][kt] = wfrag(Whh0 + (size_t)wrow*HH + kt*32 + lq*8);
    }
    __syncthreads();

    s8b xa[3], h0a[5];
    #pragma unroll
    for (int kt = 0; kt < 5; ++kt) h0a[kt] = zf;
    float c0[NTILE] = {0.f,0.f,0.f,0.f,0.f};

    const float* xb = x + (size_t)(b0 + lr) * TT * II;
    {
      float4 a0 = ld4(xb + lq*8),      a1 = ld4(xb + lq*8 + 4);
      float4 a2 = ld4(xb + 32 + lq*8), a3 = ld4(xb + 32 + lq*8 + 4);
      const float* x2 = (lq < 2) ? xb + 64 + lq*8 : xb;
      float4 a4 = ld4(x2), a5 = ld4(x2 + 4);
      xa[0] = pack8(a0,a1); xa[1] = pack8(a2,a3);
      xa[2] = (lq < 2) ? pack8(a4,a5) : zf;
    }
    // accx(0) = bias + Wih0*x(0): off-critical precompute, in place
    f4 accx[NTILE];
    #pragma unroll
    for (int s = 0; s < NTILE; ++s){
      accx[s] = (f4){bias0[s], bias0[s], bias0[s], bias0[s]};
      accx[s] = mfma16(xa[0], *(const s8b*)(smem + ((w*10 + s*2 + 0) << 10) + (l << 4)), accx[s]);
      accx[s] = mfma16(xa[1], *(const s8b*)(smem + ((w*10 + s*2 + 1) << 10) + (l << 4)), accx[s]);
      accx[s] = mfma16(xa[2], Wi2[s], accx[s]);
    }

    int credB = 0;
    for (int t = 0; t < TT; ++t){
      const int tn = (t+1 < TT) ? t+1 : t;             // x(t+1) prefetch
      const float* xr = xb + (size_t)tn * II;
      float4 n0 = ld4(xr + lq*8),      n1 = ld4(xr + lq*8 + 4);
      float4 n2 = ld4(xr + 32 + lq*8), n3 = ld4(xr + 32 + lq*8 + 4);
      const float* x2 = (lq < 2) ? xr + 64 + lq*8 : xr;
      float4 n4 = ld4(x2), n5 = ld4(x2 + 4);

      if (t >= DEPTH && credB < t - DEPTH + 1)
        poll_ge(prog, credB, t - DEPTH + 1, l);        // slot-reuse credit

      short* hb = hsh + (t&1)*16*HP;
      // ---- critical block: 25 pure-register MFMAs (5 indep 5-deep chains)
      #pragma unroll
      for (int kt = 0; kt < 5; ++kt)
        #pragma unroll
        for (int s = 0; s < NTILE; ++s)
          accx[s] = mfma16(h0a[kt], Wh[s][kt], accx[s]);
      // ---- gates
      #pragma unroll
      for (int s = 0; s < NTILE; ++s){
        float gv[4]; qtrans(accx[s], q, gv);
        const float cn = sigf(gv[1])*c0[s] + sigf(gv[0])*tanh_(gv[2]);
        c0[s] = cn;
        const float h = sigf(gv[3])*tanh_(cn);
        hb[(lq*4 + q)*HP + 4*(w + 8*s) + h2] = f2bf(h);
      }
      __syncthreads();                                 // h0(t) visible
      #pragma unroll
      for (int kt = 0; kt < 5; ++kt)
        h0a[kt] = *(const s8b*)&hb[lr*HP + kt*32 + lq*8];
      if (w < 5){                                      // ship frag kt=w, tagged t
        const s8b hf = h0a[w];
        const unsigned long long tg = (unsigned long long)t;
        unsigned long long u0 = (unsigned long long)(unsigned short)hf[0]
                              | ((unsigned long long)(unsigned short)hf[1] << 16)
                              | ((unsigned long long)(unsigned short)hf[2] << 32)
                              | (tg << 48);
        unsigned long long u1 = (unsigned long long)(unsigned short)hf[3]
                              | ((unsigned long long)(unsigned short)hf[4] << 16)
                              | ((unsigned long long)(unsigned short)hf[5] << 32)
                              | (tg << 48);
        unsigned long long u2 = (unsigned long long)(unsigned short)hf[6]
                              | ((unsigned long long)(unsigned short)hf[7] << 16)
                              | (tg << 32) | (tg << 48);
        unsigned long long* dst = ring + (size_t)(t & (DEPTH-1))*SLOT_U64 + (w*64 + l)*3;
        st64(dst, u0); st64(dst+1, u1); st64(dst+2, u2);
        // no drain, no flag: tags self-validate; stores ack during next step
      }
      xa[0] = pack8(n0,n1); xa[1] = pack8(n2,n3);
      xa[2] = (lq < 2) ? pack8(n4,n5) : zf;
      // ---- precompute accx(t+1) = bias + Wih0*x(t+1): hides h0a ds_read
      //      latency; Wih0 LDS reads are now off the critical path.
      #pragma unroll
      for (int s = 0; s < NTILE; ++s){
        accx[s] = (f4){bias0[s], bias0[s], bias0[s], bias0[s]};
        accx[s] = mfma16(xa[0], *(const s8b*)(smem + ((w*10 + s*2 + 0) << 10) + (l << 4)), accx[s]);
        accx[s] = mfma16(xa[1], *(const s8b*)(smem + ((w*10 + s*2 + 1) << 10) + (l << 4)), accx[s]);
        accx[s] = mfma16(xa[2], Wi2[s], accx[s]);
      }
    }
  }
  else {
    // ================= stage B: layer 1 + head =================
    short* h0l = (short*)(smem + H0L_OFF);             // [2][16*HP]
    float* ypart = (float*)(smem + YP_OFF);            // [2][8][16]
    float* biassh = (float*)(smem + BS_OFF);
    float* woutsh = (float*)(smem + WO_OFF);
    for (int i = tid; i < 640; i += NTHR){
      const int ct = i >> 4, r = i & 15;
      const int row = (r&3)*HH + 4*ct + (r>>2);
      biassh[i] = bih1[row] + bhh1[row];
    }
    for (int i = tid; i < HH; i += NTHR) woutsh[i] = Wout[i];
    // SWAP vs round-3: Whh1 ALL 25 frags in regs (on-path); Wih1 kt0..2 in
    // regs, Wih1 kt3,4 in LDS (only touched by the off-path precompute).
    s8b Wi[NTILE][3], Wh[NTILE][5];
    float woutv[NTILE];
    #pragma unroll
    for (int s = 0; s < NTILE; ++s){
      const int ct = w + 8*s;
      const int wrow = q*HH + 4*ct + h2;
      woutv[s] = Wout[4*ct + h2];
      #pragma unroll
      for (int kt = 0; kt < 5; ++kt)
        Wh[s][kt] = wfrag(Whh1 + (size_t)wrow*HH + kt*32 + lq*8);
      #pragma unroll
      for (int kt = 0; kt < 3; ++kt)
        Wi[s][kt] = wfrag(Wih1 + (size_t)wrow*HH + kt*32 + lq*8);
      #pragma unroll
      for (int kt = 3; kt < 5; ++kt)
        *(s8b*)(smem + ((w*10 + s*2 + (kt-3)) << 10) + (l << 4)) =
            wfrag(Wih1 + (size_t)wrow*HH + kt*32 + lq*8);
    }
    const float bo = bout[0];
    s8b h1a[5];
    #pragma unroll
    for (int kt = 0; kt < 5; ++kt) h1a[kt] = zf;
    float c1[NTILE] = {0.f,0.f,0.f,0.f,0.f};

    // prologue: spin-consume slot 0 -> h0l[0]; issue speculative loads slot 1
    unsigned long long in0 = 0, in1 = 0, in2 = 0;
    if (w < 5){
      const unsigned long long* src = ring + (w*64 + l)*3;
      in0 = ld64(src); in1 = ld64(src+1); in2 = ld64(src+2);
      bool ok = ((int)(in0>>48)==0) && ((int)(in1>>48)==0) && ((int)(in2>>48)==0);
      while (__ballot(ok) != ~0ull){
        __builtin_amdgcn_s_sleep(1);
        in0 = ld64(src); in1 = ld64(src+1); in2 = ld64(src+2);
        ok = ((int)(in0>>48)==0) && ((int)(in1>>48)==0) && ((int)(in2>>48)==0);
      }
      s8b v;
      v[0]=(short)in0; v[1]=(short)(in0>>16); v[2]=(short)(in0>>32);
      v[3]=(short)in1; v[4]=(short)(in1>>16); v[5]=(short)(in1>>32);
      v[6]=(short)in2; v[7]=(short)(in2>>16);
      *(s8b*)&h0l[lr*HP + w*32 + lq*8] = v;
      const unsigned long long* p1 = ring + (size_t)(1 & (DEPTH-1))*SLOT_U64 + (w*64 + l)*3;
      in0 = ld64(p1); in1 = ld64(p1+1); in2 = ld64(p1+2);
    }
    __syncthreads();

    // accx(0) = bias + Wih1*h0(0): off-critical precompute, in place
    f4 accx[NTILE];
    {
      const short* hp = h0l;                           // buffer 0 holds h0(0)
      #pragma unroll
      for (int s = 0; s < NTILE; ++s){
        const float b = biassh[(w + 8*s)*16 + lr];
        accx[s] = (f4){b, b, b, b};
      }
      #pragma unroll
      for (int kt = 0; kt < 3; ++kt){
        const s8b hf = *(const s8b*)&hp[lr*HP + kt*32 + lq*8];
        #pragma unroll
        for (int s = 0; s < NTILE; ++s) accx[s] = mfma16(hf, Wi[s][kt], accx[s]);
      }
      #pragma unroll
      for (int kt = 3; kt < 5; ++kt){
        const s8b hf = *(const s8b*)&hp[lr*HP + kt*32 + lq*8];
        #pragma unroll
        for (int s = 0; s < NTILE; ++s)
          accx[s] = mfma16(hf, *(const s8b*)(smem + ((w*10 + s*2 + (kt-3)) << 10) + (l << 4)), accx[s]);
      }
    }

    for (int t = 0; t < TT; ++t){
      short* hb = hsh + (t&1)*16*HP;
      // ---- critical block: 25 pure-register MFMAs (5 indep 5-deep chains)
      #pragma unroll
      for (int kt = 0; kt < 5; ++kt)
        #pragma unroll
        for (int s = 0; s < NTILE; ++s)
          accx[s] = mfma16(h1a[kt], Wh[s][kt], accx[s]);

      // validate slot t+1 (loads issued last step), stage into h0l[(t+1)&1]
      // (runs in the shadow of the MFMA block above)
      if (w < 5 && t+1 < TT){
        const int tg = t+1;
        const unsigned long long* src =
            ring + (size_t)(tg & (DEPTH-1))*SLOT_U64 + (w*64 + l)*3;
        bool ok = ((int)(in0>>48)==tg) && ((int)(in1>>48)==tg) && ((int)(in2>>48)==tg);
        while (__ballot(ok) != ~0ull){
          __builtin_amdgcn_s_sleep(1);
          in0 = ld64(src); in1 = ld64(src+1); in2 = ld64(src+2);
          ok = ((int)(in0>>48)==tg) && ((int)(in1>>48)==tg) && ((int)(in2>>48)==tg);
        }
        s8b v;
        v[0]=(short)in0; v[1]=(short)(in0>>16); v[2]=(short)(in0>>32);
        v[3]=(short)in1; v[4]=(short)(in1>>16); v[5]=(short)(in1>>32);
        v[6]=(short)in2; v[7]=(short)(in2>>16);
        *(s8b*)&h0l[((t+1)&1)*16*HP + lr*HP + w*32 + lq*8] = v;
      }

      // ---- gates + head partials
      float ysum = 0.f;
      #pragma unroll
      for (int s = 0; s < NTILE; ++s){
        float gv[4]; qtrans(accx[s], q, gv);
        const float cn = sigf(gv[1])*c1[s] + sigf(gv[0])*tanh_(gv[2]);
        c1[s] = cn;
        const float h = sigf(gv[3])*tanh_(cn);
        hb[(lq*4 + q)*HP + 4*(w + 8*s) + h2] = f2bf(h);
        ysum += h * woutv[s];
      }
      ysum += __shfl_xor(ysum, 4, 64);
      ysum += __shfl_xor(ysum, 8, 64);
      if ((l & 12) == 0) ypart[(t&1)*128 + w*16 + lq*4 + q] = ysum;

      __syncthreads();                                 // h1(t), ypart, h0(t+1) visible
      #pragma unroll
      for (int kt = 0; kt < 5; ++kt)
        h1a[kt] = *(const s8b*)&hb[lr*HP + kt*32 + lq*8];
      if (w == 0 && l < 16){
        float s_ = bo;
        #pragma unroll
        for (int ww = 0; ww < NW; ++ww) s_ += ypart[(t&1)*128 + ww*16 + l];
        out[(size_t)(b0 + l)*TT + t] = fmaxf(s_, 0.f);
      }
      // ---- precompute accx(t+1) = bias + Wih1*h0(t+1): hides h1a ds_read
      //      latency; all weight LDS reads are off the critical path.
      //      (at t==TT-1 this reads stale LDS; result is never used)
      {
        const short* hp = h0l + ((t+1)&1)*16*HP;
        #pragma unroll
        for (int s = 0; s < NTILE; ++s){
          const float b = biassh[(w + 8*s)*16 + lr];
          accx[s] = (f4){b, b, b, b};
        }
        #pragma unroll
        for (int kt = 0; kt < 3; ++kt){
          const s8b hf = *(const s8b*)&hp[lr*HP + kt*32 + lq*8];
          #pragma unroll
          for (int s = 0; s < NTILE; ++s) accx[s] = mfma16(hf, Wi[s][kt], accx[s]);
        }
        #pragma unroll
        for (int kt = 3; kt < 5; ++kt){
          const s8b hf = *(const s8b*)&hp[lr*HP + kt*32 + lq*8];
          #pragma unroll
          for (int s = 0; s < NTILE; ++s)
            accx[s] = mfma16(hf, *(const s8b*)(smem + ((w*10 + s*2 + (kt-3)) << 10) + (l << 4)), accx[s]);
        }
      }
      if (w < 5 && t+2 < TT){                          // speculative loads slot t+2
        const unsigned long long* p =
            ring + (size_t)((t+2) & (DEPTH-1))*SLOT_U64 + (w*64 + l)*3;
        in0 = ld64(p); in1 = ld64(p+1); in2 = ld64(p+2);
      }
      if (((t & 7) == 7) && tid == 0)                  // credit, post-barrier = free
        __hip_atomic_store(prog, t+1, __ATOMIC_RELEASE, __HIP_MEMORY_SCOPE_AGENT);
    }
  }
}

extern "C" void kernel_launch(void* const* d_in, const int* in_sizes, int n_in,
                              void* d_out, int out_size, void* d_ws, size_t ws_size,
                              hipStream_t stream)
{
  (void)in_sizes; (void)n_in; (void)out_size; (void)ws_size;
  (void)hipFuncSetAttribute(reinterpret_cast<const void*>(lstm2),
                            hipFuncAttributeMaxDynamicSharedMemorySize, SMEM_SZ);
  (void)hipMemsetAsync(d_ws, 0, 4096, stream);   // credit counters
  lstm2<<<dim3(NGRP*2), dim3(NTHR), SMEM_SZ, stream>>>(
      (const float*)d_in[0],
      (const float*)d_in[1], (const float*)d_in[2],
      (const float*)d_in[3], (const float*)d_in[4],
      (const float*)d_in[5], (const float*)d_in[6],
      (const float*)d_in[7], (const float*)d_in[8],
      (const float*)d_in[9], (const float*)d_in[10],
      (float*)d_out, (char*)d_ws);
}

// Round 2
// 4459.020 us; speedup vs baseline: 1.4311x; 1.1995x over previous
//
#include <hip/hip_runtime.h>
#include <stdint.h>

// 2-layer LSTM (B=512,T=1024,I=80,H=160) on MI355X gfx950.
// 2-stage pipeline, 32 groups x 2 = 64 blocks x 512 thr (8 waves, 2/SIMD).
// Round-5: VALU diet (kernel is VALU-issue-bound on active SIMDs at low
// effective clock; counters: active-SIMD VALUBusy ~60%, MfmaUtil ~12%).
//  - MFMA OPERAND SWAP: weights as A-operand -> 4 gates of one unit land in
//    the 4 acc regs of one lane. qtrans (DPP+selects, ~100 VALU/wave/step)
//    DELETED. Weight load addressing is UNCHANGED (frag layouts symmetric).
//  - v_rcp_f32 for sigmoid/tanh (was IEEE div = rcp+Newton chains).
//  - x de-dup: wave 7 packs x(t+1) -> LDS dbuf; others ds_read (was 8x
//    redundant global load + 144 f2bf per wave).
//  - Ring layout [word][lane]: dense 512B stores (was 3x write-through
//    amplification, WRITE_SIZE 757MB for 253MB of payload).
// Ring protocol unchanged: self-validating tags, DEPTH=32, credit every 8.

#define TT 1024
#define BATCH 512
#define II 80
#define HH 160

constexpr int BB    = 16;
constexpr int NGRP  = BATCH / BB;   // 32
constexpr int NW    = 8;
constexpr int NTHR  = NW * 64;      // 512
constexpr int NTILE = 5;            // 40 col-tiles / 8 waves
constexpr int DEPTH = 32;           // ring depth (power of 2)
constexpr int HP    = 168;          // LDS h row stride (shorts)
constexpr int XP    = 88;           // LDS x row stride (shorts)

typedef __attribute__((ext_vector_type(8))) short s8b;
typedef __attribute__((ext_vector_type(4))) short s4b;
typedef __attribute__((ext_vector_type(4))) float f4;

// ring: per slot, 3 words x 320 lanes (u64) = 960 u64 = 7680 B, word-major
constexpr int SLOT_U64 = 960;
constexpr size_t OFF_RING = 4096;
constexpr size_t RING_STRIDE = (size_t)DEPTH * SLOT_U64 * 8;   // 245760 B/group

// dynamic LDS layout (bytes)
constexpr int HSH_OFF = 81920;    // h dbuf [2][16*HP] shorts (10752)
constexpr int H0L_OFF = 92672;    // B: h0 dbuf [2][16*HP]; A: xsh dbuf [2][16*XP]
constexpr int YP_OFF  = 103424;   // B: ypart [2][8][16] float (1024)
constexpr int BS_OFF  = 104448;   // B: bias4 [160] f4 (2560)
constexpr int SMEM_SZ = 107648;

__device__ __forceinline__ short f2bf(float x){
  uint32_t u = __builtin_bit_cast(uint32_t, x);
  u = (u + 0x7FFFu + ((u >> 16) & 1u)) >> 16;     // RNE
  return (short)u;
}
__device__ __forceinline__ float rcpf(float x){
  float r;
  asm("v_rcp_f32 %0, %1" : "=v"(r) : "v"(x));
  return r;
}
__device__ __forceinline__ float sigf(float x){ return rcpf(1.f + __expf(-x)); }
__device__ __forceinline__ float tanh_(float x){ return 1.f - 2.f*rcpf(__expf(2.f*x)+1.f); }

__device__ __forceinline__ f4 mfma16(s8b a, s8b b, f4 c){
  return __builtin_amdgcn_mfma_f32_16x16x32_bf16(a, b, c, 0, 0, 0);
}

__device__ __forceinline__ s8b pack8(float4 a, float4 b){
  s8b r;
  r[0]=f2bf(a.x); r[1]=f2bf(a.y); r[2]=f2bf(a.z); r[3]=f2bf(a.w);
  r[4]=f2bf(b.x); r[5]=f2bf(b.y); r[6]=f2bf(b.z); r[7]=f2bf(b.w);
  return r;
}
__device__ __forceinline__ float4 ld4(const float* p){ return *(const float4*)p; }
__device__ __forceinline__ s8b wfrag(const float* p){ return pack8(ld4(p), ld4(p+4)); }

__device__ __forceinline__ void st64(unsigned long long* p, unsigned long long v){
  __hip_atomic_store(p, v, __ATOMIC_RELAXED, __HIP_MEMORY_SCOPE_AGENT);
}
__device__ __forceinline__ unsigned long long ld64(const unsigned long long* p){
  return __hip_atomic_load(p, __ATOMIC_RELAXED, __HIP_MEMORY_SCOPE_AGENT);
}
__device__ __forceinline__ void poll_ge(int* p, int& shadow, int target, int lane){
  while (shadow < target){
    int v = 0;
    if (lane == 0) v = __hip_atomic_load(p, __ATOMIC_ACQUIRE, __HIP_MEMORY_SCOPE_AGENT);
    shadow = __shfl(v, 0, 64);
    if (shadow < target) __builtin_amdgcn_s_sleep(2);
  }
}

__global__ __launch_bounds__(NTHR, 1)   // block=512: 2 waves/SIMD -> 256-reg cap
void lstm2(const float* __restrict__ x,
           const float* __restrict__ Wih0, const float* __restrict__ Whh0,
           const float* __restrict__ bih0, const float* __restrict__ bhh0,
           const float* __restrict__ Wih1, const float* __restrict__ Whh1,
           const float* __restrict__ bih1, const float* __restrict__ bhh1,
           const float* __restrict__ Wout, const float* __restrict__ bout,
           float* __restrict__ out, char* __restrict__ ws)
{
  extern __shared__ char smem[];
  const int tid = threadIdx.x;
  const int w   = tid >> 6;
  const int l   = tid & 63;
  const int lq  = l >> 4;
  const int lr  = l & 15;
  const int q   = l & 3;          // = lr&3 (weight-row gate index)
  const int h2  = (l >> 2) & 3;   // = lr>>2 (weight-row unit-sub index)
  const int stage = blockIdx.x >> 5;
  const int gid   = blockIdx.x & 31;
  const int b0    = gid * BB;
  const int li    = w*64 + l;     // ring lane index (word-major layout)

  int* prog = (int*)ws + gid;   // consumer progress (credit to A)
  unsigned long long* ring =
      (unsigned long long*)(ws + OFF_RING + (size_t)gid * RING_STRIDE);

  short* hsh = (short*)(smem + HSH_OFF);                // [2][16*HP]
  const s8b zf = {};

  if (stage == 0){
    // ================= stage A: layer 0 =================
    // Whh0 (25 frags) + Wih0 kt2 (5) in regs; Wih0 kt0,1 (10) in LDS.
    short* xsh = (short*)(smem + H0L_OFF);              // [2][16*XP]
    s8b Wh[NTILE][5], Wi2[NTILE];
    f4 biasv[NTILE];
    #pragma unroll
    for (int s = 0; s < NTILE; ++s){
      const int ct = w + 8*s;
      const int wrow = q*HH + 4*ct + h2;
      const int u = 4*ct + lq;                          // per-lane unit
      #pragma unroll
      for (int g = 0; g < 4; ++g)
        biasv[s][g] = bih0[g*HH + u] + bhh0[g*HH + u];
      #pragma unroll
      for (int kt = 0; kt < 2; ++kt)
        *(s8b*)(smem + ((w*10 + s*2 + kt) << 10) + (l << 4)) =
            wfrag(Wih0 + (size_t)wrow*II + kt*32 + lq*8);
      Wi2[s] = (lq < 2) ? wfrag(Wih0 + (size_t)wrow*II + 64 + lq*8) : zf;
      #pragma unroll
      for (int kt = 0; kt < 5; ++kt)
        Wh[s][kt] = wfrag(Whh0 + (size_t)wrow*HH + kt*32 + lq*8);
    }
    if (w == 7){                                        // pack x(0) -> xsh buf0
      const float* xp = x + (size_t)(b0 + lr) * TT * II + (l>>4)*20;
      short* xd = xsh + lr*XP + (l>>4)*20;
      #pragma unroll
      for (int i = 0; i < 5; ++i){
        float4 a = ld4(xp + i*4);
        s4b p; p[0]=f2bf(a.x); p[1]=f2bf(a.y); p[2]=f2bf(a.z); p[3]=f2bf(a.w);
        *(s4b*)(xd + i*4) = p;
      }
    }
    __syncthreads();                                    // weights + xsh[0]

    s8b h0a[5];
    #pragma unroll
    for (int kt = 0; kt < 5; ++kt) h0a[kt] = zf;
    float c0[NTILE] = {0.f,0.f,0.f,0.f,0.f};

    // accx(0) = bias + Wih0*x(0)
    s8b xa[3];
    {
      const short* xr = xsh + lr*XP;
      xa[0] = *(const s8b*)&xr[lq*8];
      xa[1] = *(const s8b*)&xr[32 + lq*8];
      xa[2] = (lq < 2) ? *(const s8b*)&xr[64 + lq*8] : zf;
    }
    f4 accx[NTILE];
    #pragma unroll
    for (int s = 0; s < NTILE; ++s){
      accx[s] = biasv[s];
      accx[s] = mfma16(*(const s8b*)(smem + ((w*10 + s*2 + 0) << 10) + (l << 4)), xa[0], accx[s]);
      accx[s] = mfma16(*(const s8b*)(smem + ((w*10 + s*2 + 1) << 10) + (l << 4)), xa[1], accx[s]);
      accx[s] = mfma16(Wi2[s], xa[2], accx[s]);
    }

    int credB = 0;
    for (int t = 0; t < TT; ++t){
      float4 xl0, xl1, xl2, xl3, xl4;                   // w7: x(t+1) early issue
      if (w == 7 && t+1 < TT){
        const float* xp = x + (size_t)(b0 + lr) * TT * II + (size_t)(t+1)*II + (l>>4)*20;
        xl0 = ld4(xp); xl1 = ld4(xp+4); xl2 = ld4(xp+8); xl3 = ld4(xp+12); xl4 = ld4(xp+16);
      }

      if (t >= DEPTH && credB < t - DEPTH + 1)
        poll_ge(prog, credB, t - DEPTH + 1, l);         // slot-reuse credit

      short* hb = hsh + (t&1)*16*HP;
      // ---- critical block: 25 pure-register MFMAs (weights as A-operand)
      #pragma unroll
      for (int kt = 0; kt < 5; ++kt)
        #pragma unroll
        for (int s = 0; s < NTILE; ++s)
          accx[s] = mfma16(Wh[s][kt], h0a[kt], accx[s]);
      // ---- gates: acc regs = (i,f,g,o) of unit 4ct+lq, batch lr. No qtrans.
      #pragma unroll
      for (int s = 0; s < NTILE; ++s){
        const float cn = sigf(accx[s][1])*c0[s] + sigf(accx[s][0])*tanh_(accx[s][2]);
        c0[s] = cn;
        const float h = sigf(accx[s][3])*tanh_(cn);
        hb[lr*HP + 4*(w + 8*s) + lq] = f2bf(h);
      }
      if (w == 7 && t+1 < TT){                          // pack x(t+1) -> xsh
        short* xd = xsh + ((t+1)&1)*16*XP + lr*XP + (l>>4)*20;
        float4 a[5] = {xl0, xl1, xl2, xl3, xl4};
        #pragma unroll
        for (int i = 0; i < 5; ++i){
          s4b p; p[0]=f2bf(a[i].x); p[1]=f2bf(a[i].y); p[2]=f2bf(a[i].z); p[3]=f2bf(a[i].w);
          *(s4b*)(xd + i*4) = p;
        }
      }
      __syncthreads();                                  // h0(t) + x(t+1) visible
      #pragma unroll
      for (int kt = 0; kt < 5; ++kt)
        h0a[kt] = *(const s8b*)&hb[lr*HP + kt*32 + lq*8];
      if (w < 5){                                       // ship frag kt=w, tagged t
        const s8b hf = h0a[w];
        const unsigned long long tg = (unsigned long long)t;
        unsigned long long u0 = (unsigned long long)(unsigned short)hf[0]
                              | ((unsigned long long)(unsigned short)hf[1] << 16)
                              | ((unsigned long long)(unsigned short)hf[2] << 32)
                              | (tg << 48);
        unsigned long long u1 = (unsigned long long)(unsigned short)hf[3]
                              | ((unsigned long long)(unsigned short)hf[4] << 16)
                              | ((unsigned long long)(unsigned short)hf[5] << 32)
                              | (tg << 48);
        unsigned long long u2 = (unsigned long long)(unsigned short)hf[6]
                              | ((unsigned long long)(unsigned short)hf[7] << 16)
                              | (tg << 32) | (tg << 48);
        unsigned long long* sl = ring + (size_t)(t & (DEPTH-1))*SLOT_U64;
        st64(sl + li, u0); st64(sl + 320 + li, u1); st64(sl + 640 + li, u2);
      }
      // ---- precompute accx(t+1) = bias + Wih0*x(t+1) (off-critical; hides
      //      h0a ds_read latency; stale read at t=TT-1 is discarded)
      {
        const short* xr = xsh + ((t+1)&1)*16*XP + lr*XP;
        xa[0] = *(const s8b*)&xr[lq*8];
        xa[1] = *(const s8b*)&xr[32 + lq*8];
        xa[2] = (lq < 2) ? *(const s8b*)&xr[64 + lq*8] : zf;
      }
      #pragma unroll
      for (int s = 0; s < NTILE; ++s){
        accx[s] = biasv[s];
        accx[s] = mfma16(*(const s8b*)(smem + ((w*10 + s*2 + 0) << 10) + (l << 4)), xa[0], accx[s]);
        accx[s] = mfma16(*(const s8b*)(smem + ((w*10 + s*2 + 1) << 10) + (l << 4)), xa[1], accx[s]);
        accx[s] = mfma16(Wi2[s], xa[2], accx[s]);
      }
    }
  }
  else {
    // ================= stage B: layer 1 + head =================
    short* h0l = (short*)(smem + H0L_OFF);             // [2][16*HP]
    float* ypart = (float*)(smem + YP_OFF);            // [2][8][16]
    f4* bias4 = (f4*)(smem + BS_OFF);                  // [160] per-unit gate bias
    for (int i = tid; i < HH; i += NTHR){
      f4 b;
      #pragma unroll
      for (int g = 0; g < 4; ++g) b[g] = bih1[g*HH + i] + bhh1[g*HH + i];
      bias4[i] = b;
    }
    // Whh1 ALL 25 frags in regs (on-path); Wih1 kt0..2 regs, kt3,4 LDS.
    s8b Wi[NTILE][3], Wh[NTILE][5];
    float woutv[NTILE];
    #pragma unroll
    for (int s = 0; s < NTILE; ++s){
      const int ct = w + 8*s;
      const int wrow = q*HH + 4*ct + h2;
      woutv[s] = Wout[4*ct + lq];
      #pragma unroll
      for (int kt = 0; kt < 5; ++kt)
        Wh[s][kt] = wfrag(Whh1 + (size_t)wrow*HH + kt*32 + lq*8);
      #pragma unroll
      for (int kt = 0; kt < 3; ++kt)
        Wi[s][kt] = wfrag(Wih1 + (size_t)wrow*HH + kt*32 + lq*8);
      #pragma unroll
      for (int kt = 3; kt < 5; ++kt)
        *(s8b*)(smem + ((w*10 + s*2 + (kt-3)) << 10) + (l << 4)) =
            wfrag(Wih1 + (size_t)wrow*HH + kt*32 + lq*8);
    }
    const float bo = bout[0];
    s8b h1a[5];
    #pragma unroll
    for (int kt = 0; kt < 5; ++kt) h1a[kt] = zf;
    float c1[NTILE] = {0.f,0.f,0.f,0.f,0.f};

    // prologue: spin-consume slot 0 -> h0l[0]; issue speculative loads slot 1
    unsigned long long in0 = 0, in1 = 0, in2 = 0;
    if (w < 5){
      const unsigned long long* src = ring;
      in0 = ld64(src + li); in1 = ld64(src + 320 + li); in2 = ld64(src + 640 + li);
      bool ok = ((int)(in0>>48)==0) && ((int)(in1>>48)==0) && ((int)(in2>>48)==0);
      while (__ballot(ok) != ~0ull){
        __builtin_amdgcn_s_sleep(1);
        in0 = ld64(src + li); in1 = ld64(src + 320 + li); in2 = ld64(src + 640 + li);
        ok = ((int)(in0>>48)==0) && ((int)(in1>>48)==0) && ((int)(in2>>48)==0);
      }
      s8b v;
      v[0]=(short)in0; v[1]=(short)(in0>>16); v[2]=(short)(in0>>32);
      v[3]=(short)in1; v[4]=(short)(in1>>16); v[5]=(short)(in1>>32);
      v[6]=(short)in2; v[7]=(short)(in2>>16);
      *(s8b*)&h0l[lr*HP + w*32 + lq*8] = v;
      const unsigned long long* p1 = ring + (size_t)(1 & (DEPTH-1))*SLOT_U64;
      in0 = ld64(p1 + li); in1 = ld64(p1 + 320 + li); in2 = ld64(p1 + 640 + li);
    }
    __syncthreads();

    // accx(0) = bias + Wih1*h0(0)
    f4 accx[NTILE];
    {
      const short* hp = h0l;
      #pragma unroll
      for (int s = 0; s < NTILE; ++s)
        accx[s] = bias4[4*(w + 8*s) + lq];
      #pragma unroll
      for (int kt = 0; kt < 3; ++kt){
        const s8b hf = *(const s8b*)&hp[lr*HP + kt*32 + lq*8];
        #pragma unroll
        for (int s = 0; s < NTILE; ++s) accx[s] = mfma16(Wi[s][kt], hf, accx[s]);
      }
      #pragma unroll
      for (int kt = 3; kt < 5; ++kt){
        const s8b hf = *(const s8b*)&hp[lr*HP + kt*32 + lq*8];
        #pragma unroll
        for (int s = 0; s < NTILE; ++s)
          accx[s] = mfma16(*(const s8b*)(smem + ((w*10 + s*2 + (kt-3)) << 10) + (l << 4)), hf, accx[s]);
      }
    }

    for (int t = 0; t < TT; ++t){
      short* hb = hsh + (t&1)*16*HP;
      // ---- critical block: 25 pure-register MFMAs
      #pragma unroll
      for (int kt = 0; kt < 5; ++kt)
        #pragma unroll
        for (int s = 0; s < NTILE; ++s)
          accx[s] = mfma16(Wh[s][kt], h1a[kt], accx[s]);

      // validate slot t+1 (loads issued last step), stage into h0l[(t+1)&1]
      if (w < 5 && t+1 < TT){
        const int tg = t+1;
        const unsigned long long* src = ring + (size_t)(tg & (DEPTH-1))*SLOT_U64;
        bool ok = ((int)(in0>>48)==tg) && ((int)(in1>>48)==tg) && ((int)(in2>>48)==tg);
        while (__ballot(ok) != ~0ull){
          __builtin_amdgcn_s_sleep(1);
          in0 = ld64(src + li); in1 = ld64(src + 320 + li); in2 = ld64(src + 640 + li);
          ok = ((int)(in0>>48)==tg) && ((int)(in1>>48)==tg) && ((int)(in2>>48)==tg);
        }
        s8b v;
        v[0]=(short)in0; v[1]=(short)(in0>>16); v[2]=(short)(in0>>32);
        v[3]=(short)in1; v[4]=(short)(in1>>16); v[5]=(short)(in1>>32);
        v[6]=(short)in2; v[7]=(short)(in2>>16);
        *(s8b*)&h0l[((t+1)&1)*16*HP + lr*HP + w*32 + lq*8] = v;
      }

      // ---- gates + head partials (acc regs = i,f,g,o directly)
      float ysum = 0.f;
      #pragma unroll
      for (int s = 0; s < NTILE; ++s){
        const float cn = sigf(accx[s][1])*c1[s] + sigf(accx[s][0])*tanh_(accx[s][2]);
        c1[s] = cn;
        const float h = sigf(accx[s][3])*tanh_(cn);
        hb[lr*HP + 4*(w + 8*s) + lq] = f2bf(h);
        ysum += h * woutv[s];
      }
      ysum += __shfl_xor(ysum, 16, 64);
      ysum += __shfl_xor(ysum, 32, 64);
      if (l < 16) ypart[(t&1)*128 + w*16 + l] = ysum;

      __syncthreads();                                 // h1(t), ypart, h0(t+1) visible
      #pragma unroll
      for (int kt = 0; kt < 5; ++kt)
        h1a[kt] = *(const s8b*)&hb[lr*HP + kt*32 + lq*8];
      if (w == 0 && l < 16){
        float s_ = bo;
        #pragma unroll
        for (int ww = 0; ww < NW; ++ww) s_ += ypart[(t&1)*128 + ww*16 + l];
        out[(size_t)(b0 + l)*TT + t] = fmaxf(s_, 0.f);
      }
      // ---- precompute accx(t+1) = bias + Wih1*h0(t+1) (off-critical;
      //      stale read at t=TT-1 is discarded)
      {
        const short* hp = h0l + ((t+1)&1)*16*HP;
        #pragma unroll
        for (int s = 0; s < NTILE; ++s)
          accx[s] = bias4[4*(w + 8*s) + lq];
        #pragma unroll
        for (int kt = 0; kt < 3; ++kt){
          const s8b hf = *(const s8b*)&hp[lr*HP + kt*32 + lq*8];
          #pragma unroll
          for (int s = 0; s < NTILE; ++s) accx[s] = mfma16(Wi[s][kt], hf, accx[s]);
        }
        #pragma unroll
        for (int kt = 3; kt < 5; ++kt){
          const s8b hf = *(const s8b*)&hp[lr*HP + kt*32 + lq*8];
          #pragma unroll
          for (int s = 0; s < NTILE; ++s)
            accx[s] = mfma16(*(const s8b*)(smem + ((w*10 + s*2 + (kt-3)) << 10) + (l << 4)), hf, accx[s]);
        }
      }
      if (w < 5 && t+2 < TT){                          // speculative loads slot t+2
        const unsigned long long* p =
            ring + (size_t)((t+2) & (DEPTH-1))*SLOT_U64;
        in0 = ld64(p + li); in1 = ld64(p + 320 + li); in2 = ld64(p + 640 + li);
      }
      if (((t & 7) == 7) && tid == 0)                  // credit, post-barrier = free
        __hip_atomic_store(prog, t+1, __ATOMIC_RELEASE, __HIP_MEMORY_SCOPE_AGENT);
    }
  }
}

extern "C" void kernel_launch(void* const* d_in, const int* in_sizes, int n_in,
                              void* d_out, int out_size, void* d_ws, size_t ws_size,
                              hipStream_t stream)
{
  (void)in_sizes; (void)n_in; (void)out_size; (void)ws_size;
  (void)hipFuncSetAttribute(reinterpret_cast<const void*>(lstm2),
                            hipFuncAttributeMaxDynamicSharedMemorySize, SMEM_SZ);
  (void)hipMemsetAsync(d_ws, 0, 4096, stream);   // credit counters
  lstm2<<<dim3(NGRP*2), dim3(NTHR), SMEM_SZ, stream>>>(
      (const float*)d_in[0],
      (const float*)d_in[1], (const float*)d_in[2],
      (const float*)d_in[3], (const float*)d_in[4],
      (const float*)d_in[5], (const float*)d_in[6],
      (const float*)d_in[7], (const float*)d_in[8],
      (const float*)d_in[9], (const float*)d_in[10],
      (float*)d_out, (char*)d_ws);
}